// Round 8
// baseline (1598.226 us; speedup 1.0000x reference)
//
#include <hip/hip_runtime.h>
#include <math.h>

#define EMB 768
#define NH 12
#define HD 64
#define NL 12
#define NV 50257
#define MAXS 1024
#define S_PAST 1023
#define E3 2304
#define E4 3072

typedef unsigned int u32;

// workspace float offsets
#define WS_H    0
#define WS_QKV  768
#define WS_FC   3072
#define WS_PART 6144          // 192 * 68
#define WS_CNT  19200         // u32 region: 3 arrays of 144 counters, 16-u32 padded
#define CNT_WORDS 6912

__device__ __forceinline__ void f4add(float4& a, const float4& b) {
  a.x += b.x; a.y += b.y; a.z += b.z; a.w += b.w;
}

// low-fanin handoff primitives: padded per-entity counters (<=24 arrivals each)
__device__ __forceinline__ void bump(u32* cnt) {
  __threadfence();
  __syncthreads();
  if (threadIdx.x == 0)
    __hip_atomic_fetch_add(cnt, 1u, __ATOMIC_RELEASE, __HIP_MEMORY_SCOPE_AGENT);
}
__device__ __forceinline__ void wait_cnt(u32* cnt, u32 n) {
  if (threadIdx.x == 0) {
    while (__hip_atomic_load(cnt, __ATOMIC_ACQUIRE, __HIP_MEMORY_SCOPE_AGENT) < n)
      __builtin_amdgcn_s_sleep(2);
  }
  __syncthreads();
}

__device__ __forceinline__ void blockReduce2(float& a, float& b, volatile float* ra, volatile float* rb) {
  int lane = threadIdx.x & 63, wid = threadIdx.x >> 6;
#pragma unroll
  for (int o = 32; o > 0; o >>= 1) { a += __shfl_down(a, o); b += __shfl_down(b, o); }
  if (lane == 0) { ra[wid] = a; rb[wid] = b; }
  __syncthreads();
  if (threadIdx.x == 0) {
    ra[0] = ra[0] + ra[1] + ra[2] + ra[3];
    rb[0] = rb[0] + rb[1] + rb[2] + rb[3];
  }
  __syncthreads();
  a = ra[0]; b = rb[0];
}

__device__ __forceinline__ float gelu(float x) {
  return 0.5f * x * (1.f + tanhf(0.7978845608028654f * (x + 0.044715f * x * x * x)));
}

// init: h = wte[id]+wpe[S]; zero all handoff counters
__global__ void init_kernel(const int* __restrict__ ids, const float* __restrict__ wte,
                            const float* __restrict__ wpe, float* __restrict__ wsf) {
  int tid = threadIdx.x;
  if (blockIdx.x < 3) {
    int e = blockIdx.x * 256 + tid;
    int id = ids[0];
    wsf[WS_H + e] = wte[(size_t)id * EMB + e] + wpe[(size_t)S_PAST * EMB + e];
  } else {
    u32* c = (u32*)(wsf + WS_CNT);
    for (int k = tid; k < CNT_WORDS; k += 256) c[k] = 0;
  }
}

// ---------------- K_A: qkv producers -> attn chunks -> proj ----------------

// producer p (0..71): head h=p/6, role r=p%6 -> 32 qkv cols, full 768-deep GEMV
__device__ void phase_producer(int p, const float* __restrict__ hvec,
                               const float* __restrict__ g, const float* __restrict__ bb,
                               const float* __restrict__ W, const float* __restrict__ qb,
                               float* __restrict__ wsqkv, float* __restrict__ opk,
                               float* __restrict__ opv, int l, float* smem, u32* prodc) {
  int h = p / 6, r = p % 6;
  int cq = (r >> 1) * EMB + h * 64 + (r & 1) * 32;
  int tid = threadIdx.x;
  float* lh = smem;
  float* xs = smem + 768;
  volatile float* ra = smem + 1536; volatile float* rb = smem + 1540;
  float4* red = (float4*)(smem + 1544);
  int col4 = tid & 7, grp = tid >> 3;
  // issue h loads, then first weight batch (stats hide under weight latency)
  float hv0 = hvec[tid], hv1 = hvec[tid + 256], hv2 = hvec[tid + 512];
  const float4* W4 = (const float4*)(W + (size_t)l * EMB * E3) + (cq >> 2) + col4;
  float4 w[12];
#pragma unroll
  for (int i = 0; i < 12; i++) w[i] = W4[(size_t)(grp + 32 * i) * (E3 >> 2)];
  float gv0 = g[l * EMB + tid], gv1 = g[l * EMB + tid + 256], gv2 = g[l * EMB + tid + 512];
  float bv0 = bb[l * EMB + tid], bv1 = bb[l * EMB + tid + 256], bv2 = bb[l * EMB + tid + 512];
  lh[tid] = hv0; lh[tid + 256] = hv1; lh[tid + 512] = hv2;
  float s1 = hv0 + hv1 + hv2, s2 = hv0 * hv0 + hv1 * hv1 + hv2 * hv2;
  blockReduce2(s1, s2, ra, rb);
  float mean = s1 * (1.f / EMB);
  float var = s2 * (1.f / EMB) - mean * mean;
  float rstd = rsqrtf(var + 1e-5f);
  xs[tid]       = (hv0 - mean) * rstd * gv0 + bv0;
  xs[tid + 256] = (hv1 - mean) * rstd * gv1 + bv1;
  xs[tid + 512] = (hv2 - mean) * rstd * gv2 + bv2;
  __syncthreads();
  float4 acc = {0.f, 0.f, 0.f, 0.f};
#pragma unroll
  for (int i = 0; i < 12; i++) {
    float x = xs[grp + 32 * i];
    acc.x += x * w[i].x; acc.y += x * w[i].y; acc.z += x * w[i].z; acc.w += x * w[i].w;
  }
#pragma unroll
  for (int i = 0; i < 12; i++) w[i] = W4[(size_t)(grp + 32 * (i + 12)) * (E3 >> 2)];
#pragma unroll
  for (int i = 0; i < 12; i++) {
    float x = xs[grp + 32 * (i + 12)];
    acc.x += x * w[i].x; acc.y += x * w[i].y; acc.z += x * w[i].z; acc.w += x * w[i].w;
  }
  red[tid] = acc;
  __syncthreads();
#pragma unroll
  for (int s = 128; s >= 8; s >>= 1) {
    if (tid < s) f4add(red[tid], red[tid + s]);
    __syncthreads();
  }
  if (tid < 8) {
    float4 o = red[tid];
    f4add(o, ((const float4*)(qb + l * E3 + cq))[tid]);
    ((float4*)wsqkv)[(cq >> 2) + tid] = o;
    if (r >= 2) {   // new K/V slot -> output cache
      size_t base = ((size_t)(l * NH + h) * MAXS) * HD;
      float* dst = (r < 4) ? opk : opv;
      ((float4*)(dst + base))[(size_t)S_PAST * 16 + (r & 1) * 8 + tid] = o;
    }
  }
  bump(prodc);
}

// attn chunk (head h, 64-key chunk c): prefetch K/V, poll q, score+partial+PV+copy-out
__device__ void phase_attn(int a, const float* __restrict__ wsqkv,
                           const float* __restrict__ pk, const float* __restrict__ pv,
                           const float* __restrict__ mask, float* __restrict__ opk,
                           float* __restrict__ opv, float* __restrict__ part,
                           int l, float* smem, u32* prodc, u32* chc) {
  int h = a >> 4, c = a & 15;
  int tid = threadIdx.x, lane = tid & 63, wid = tid >> 6;
  int sub = tid & 15, grp = tid >> 4;
  float4* qs4 = (float4*)smem;
  float* sc = smem + 64;
  float4* redo = (float4*)(smem + 128);
  size_t base = ((size_t)(l * NH + h) * MAXS) * HD;
  const float4* K4 = (const float4*)(pk + base);
  const float4* V4 = (const float4*)(pv + base);
  int t0 = c * 64;
  float4 kreg[4], vreg[4];
#pragma unroll
  for (int i = 0; i < 4; i++) {
    int t = t0 + grp + i * 16;
    if (t != S_PAST) { kreg[i] = K4[(size_t)t * 16 + sub]; vreg[i] = V4[(size_t)t * 16 + sub]; }
  }
  wait_cnt(prodc, 6);
  if (tid < 16) qs4[tid] = ((const float4*)(wsqkv + h * 64))[tid];
  __syncthreads();
  if (c == 15 && grp == 15) {
    kreg[3] = ((const float4*)(wsqkv + EMB + h * 64))[sub];
    vreg[3] = ((const float4*)(wsqkv + 2 * EMB + h * 64))[sub];
  }
#pragma unroll
  for (int i = 0; i < 4; i++) {
    int t = t0 + grp + i * 16;
    if (t != S_PAST) {
      ((float4*)(opk + base))[(size_t)t * 16 + sub] = kreg[i];
      ((float4*)(opv + base))[(size_t)t * 16 + sub] = vreg[i];
    }
  }
  float4 q4 = qs4[sub];
#pragma unroll
  for (int i = 0; i < 4; i++) {
    int key = grp + i * 16;
    float pp = q4.x * kreg[i].x + q4.y * kreg[i].y + q4.z * kreg[i].z + q4.w * kreg[i].w;
    pp += __shfl_xor(pp, 1); pp += __shfl_xor(pp, 2);
    pp += __shfl_xor(pp, 4); pp += __shfl_xor(pp, 8);
    if (sub == 0) sc[key] = pp * 0.125f + (1.f - mask[t0 + key]) * (-1e9f);
  }
  __syncthreads();
  if (wid == 0) {
    float aa = sc[lane];
    float m = aa;
#pragma unroll
    for (int o = 32; o > 0; o >>= 1) m = fmaxf(m, __shfl_down(m, o));
    m = __shfl(m, 0);
    float ea = expf(aa - m);
    sc[lane] = ea;
    float s = ea;
#pragma unroll
    for (int o = 32; o > 0; o >>= 1) s += __shfl_down(s, o);
    if (lane == 0) { part[(h * 16 + c) * 68 + 0] = m; part[(h * 16 + c) * 68 + 1] = s; }
  }
  __syncthreads();
  float4 acc = {0.f, 0.f, 0.f, 0.f};
#pragma unroll
  for (int i = 0; i < 4; i++) {
    float w = sc[grp + i * 16];
    acc.x += w * vreg[i].x; acc.y += w * vreg[i].y; acc.z += w * vreg[i].z; acc.w += w * vreg[i].w;
  }
  acc.x += __shfl_xor(acc.x, 16); acc.y += __shfl_xor(acc.y, 16);
  acc.z += __shfl_xor(acc.z, 16); acc.w += __shfl_xor(acc.w, 16);
  acc.x += __shfl_xor(acc.x, 32); acc.y += __shfl_xor(acc.y, 32);
  acc.z += __shfl_xor(acc.z, 32); acc.w += __shfl_xor(acc.w, 32);
  if (lane < 16) redo[wid * 16 + lane] = acc;
  __syncthreads();
  if (tid < 16) {
    float4 a0 = redo[tid], a1 = redo[16 + tid], a2 = redo[32 + tid], a3 = redo[48 + tid];
    float4 rr;
    rr.x = a0.x + a1.x + a2.x + a3.x;
    rr.y = a0.y + a1.y + a2.y + a3.y;
    rr.z = a0.z + a1.z + a2.z + a3.z;
    rr.w = a0.w + a1.w + a2.w + a3.w;
    ((float4*)(part + (h * 16 + c) * 68 + 4))[tid] = rr;
  }
  bump(chc);
}

// proj: prefetch weights, poll chunks of head, combine + 16-row GEMV into h
__device__ void phase_proj(int pi, const float* __restrict__ part, const float* __restrict__ W,
                           const float* __restrict__ bias, const float* __restrict__ fc_b,
                           float* __restrict__ hout, float* __restrict__ wfc,
                           int l, float* smem, u32* chc) {
  int jb = pi % 3, rt = pi / 3;
  int h = rt >> 2, esub = rt & 3;
  int tid = threadIdx.x, lane = tid & 63, wid = tid >> 6;
  float* xs = smem;
  float4* red = (float4*)(smem + 16);
  int j4 = jb * 64 + lane;
  const int N4 = EMB >> 2;
  int r0 = h * 64 + esub * 16;
  const float4* p = (const float4*)(W + (size_t)l * EMB * EMB) + (size_t)(r0 + wid) * N4 + j4;
  float4 w[4];
#pragma unroll
  for (int i = 0; i < 4; i++) w[i] = p[(size_t)(i * 4) * N4];
  if (pi < 12) wfc[pi * 256 + tid] = fc_b[l * E4 + pi * 256 + tid];
  wait_cnt(chc, 16);
  if (tid < 16) {
    float M = -1e30f;
#pragma unroll
    for (int q = 0; q < 16; q++) M = fmaxf(M, part[(h * 16 + q) * 68]);
    float T = 0.f, o = 0.f;
    int d = esub * 16 + tid;
#pragma unroll
    for (int q = 0; q < 16; q++) {
      float wq = expf(part[(h * 16 + q) * 68] - M);
      T += part[(h * 16 + q) * 68 + 1] * wq;
      o += part[(h * 16 + q) * 68 + 4 + d] * wq;
    }
    xs[tid] = o / T;
  }
  __syncthreads();
  float4 acc = {0.f, 0.f, 0.f, 0.f};
#pragma unroll
  for (int i = 0; i < 4; i++) {
    float x = xs[wid + i * 4];
    acc.x += x * w[i].x; acc.y += x * w[i].y; acc.z += x * w[i].z; acc.w += x * w[i].w;
  }
  red[wid * 64 + lane] = acc;
  __syncthreads();
  if (wid == 0) {
    float4 a0 = red[lane], a1 = red[64 + lane], a2 = red[128 + lane], a3 = red[192 + lane];
    float rx = a0.x + a1.x + a2.x + a3.x;
    float ry = a0.y + a1.y + a2.y + a3.y;
    float rz = a0.z + a1.z + a2.z + a3.z;
    float rw = a0.w + a1.w + a2.w + a3.w;
    if (rt == 0) {
      const float* bp = bias + l * EMB + jb * 256 + lane * 4;
      rx += bp[0]; ry += bp[1]; rz += bp[2]; rw += bp[3];
    }
    float* op = hout + (size_t)jb * 256 + (size_t)lane * 4;
    atomicAdd(op + 0, rx); atomicAdd(op + 1, ry);
    atomicAdd(op + 2, rz); atomicAdd(op + 3, rw);
  }
}

__global__ __launch_bounds__(256, 2) void kA(
    const float* __restrict__ pk, const float* __restrict__ pv, const float* __restrict__ mask,
    const float* __restrict__ ln1_g, const float* __restrict__ ln1_b,
    const float* __restrict__ attn_w, const float* __restrict__ attn_b,
    const float* __restrict__ proj_w, const float* __restrict__ proj_b,
    const float* __restrict__ fc_b, float* __restrict__ opk, float* __restrict__ opv,
    float* __restrict__ wsf, int l) {
  __shared__ __align__(16) float smem[2568];
  u32* cnt = (u32*)(wsf + WS_CNT);
  u32* prodc = cnt;
  u32* chc = cnt + 2304;
  float* wh = wsf + WS_H;
  float* wqkv = wsf + WS_QKV;
  float* wfc = wsf + WS_FC;
  float* wpart = wsf + WS_PART;
  int bi = blockIdx.x;
  if (bi < 72) {
    int h = bi / 6;
    phase_producer(bi, wh, ln1_g, ln1_b, attn_w, attn_b, wqkv, opk, opv, l, smem,
                   prodc + (l * 12 + h) * 16);
  } else if (bi < 264) {
    int a = bi - 72;
    int h = a >> 4;
    phase_attn(a, wqkv, pk, pv, mask, opk, opv, wpart, l, smem,
               prodc + (l * 12 + h) * 16, chc + (l * 12 + h) * 16);
  } else {
    int pi = bi - 264;
    int h = (pi / 3) >> 2;
    phase_proj(pi, wpart, proj_w, proj_b, fc_b, wh, wfc, l, smem,
               chc + (l * 12 + h) * 16);
  }
}

// ---------------- K_B: fc -> mlp ----------------

__global__ __launch_bounds__(256, 2) void kB(
    const float* __restrict__ ln2_g, const float* __restrict__ ln2_b,
    const float* __restrict__ fc_w, const float* __restrict__ mlp_w,
    const float* __restrict__ mlp_b, float* __restrict__ wsf, int l) {
  __shared__ __align__(16) float smem[1840];
  u32* fcc = (u32*)(wsf + WS_CNT) + 4608;
  float* wh = wsf + WS_H;
  float* wfc = wsf + WS_FC;
  int bi = blockIdx.x, tid = threadIdx.x, lane = tid & 63, wid = tid >> 6;
  if (bi < 288) {
    // fc: 32 rows x 256 cols of LN2(h) @ fc_w -> wfc (bias pre-seeded by proj)
    int jt = bi % 12, et = bi / 12;
    float* lh = smem;
    float* xs = smem + 768;
    volatile float* ra = smem + 800; volatile float* rb = smem + 804;
    float4* red = (float4*)(smem + 816);
    int e0 = et * 32;
    float hv0 = wh[tid], hv1 = wh[tid + 256], hv2 = wh[tid + 512];
    int j4 = jt * 64 + lane;
    const int N4 = E4 >> 2;
    const float4* p = (const float4*)(fc_w + (size_t)l * EMB * E4) + (size_t)(e0 + wid) * N4 + j4;
    float4 w[8];
#pragma unroll
    for (int i = 0; i < 8; i++) w[i] = p[(size_t)(i * 4) * N4];
    float gv = 0.f, bv = 0.f;
    if (tid < 32) { gv = ln2_g[l * EMB + e0 + tid]; bv = ln2_b[l * EMB + e0 + tid]; }
    lh[tid] = hv0; lh[tid + 256] = hv1; lh[tid + 512] = hv2;
    float s1 = hv0 + hv1 + hv2, s2 = hv0 * hv0 + hv1 * hv1 + hv2 * hv2;
    blockReduce2(s1, s2, ra, rb);
    float mean = s1 * (1.f / EMB);
    float var = s2 * (1.f / EMB) - mean * mean;
    float rstd = rsqrtf(var + 1e-5f);
    if (tid < 32) xs[tid] = (lh[e0 + tid] - mean) * rstd * gv + bv;
    __syncthreads();
    float4 acc = {0.f, 0.f, 0.f, 0.f};
#pragma unroll
    for (int i = 0; i < 8; i++) {
      float x = xs[wid + i * 4];
      acc.x += x * w[i].x; acc.y += x * w[i].y; acc.z += x * w[i].z; acc.w += x * w[i].w;
    }
    red[wid * 64 + lane] = acc;
    __syncthreads();
    if (wid == 0) {
      float4 a0 = red[lane], a1 = red[64 + lane], a2 = red[128 + lane], a3 = red[192 + lane];
      float rx = a0.x + a1.x + a2.x + a3.x;
      float ry = a0.y + a1.y + a2.y + a3.y;
      float rz = a0.z + a1.z + a2.z + a3.z;
      float rw = a0.w + a1.w + a2.w + a3.w;
      float* op = wfc + (size_t)j4 * 4;
      atomicAdd(op + 0, rx); atomicAdd(op + 1, ry);
      atomicAdd(op + 2, rz); atomicAdd(op + 3, rw);
    }
    bump(fcc + (l * 12 + jt) * 16);
  } else {
    // mlp: 64 gelu rows x 256 cols into h
    int m = bi - 288;
    int jt3 = m % 3, et2 = m / 3;
    int jtf = et2 >> 2;
    float* xs = smem;
    float4* red = (float4*)(smem + 64);
    int e0 = et2 * 64;
    int j4 = jt3 * 64 + lane;
    const int N4 = EMB >> 2;
    const float4* p = (const float4*)(mlp_w + (size_t)l * E4 * EMB) + (size_t)(e0 + wid) * N4 + j4;
    float4 w[16];
#pragma unroll
    for (int i = 0; i < 16; i++) w[i] = p[(size_t)(i * 4) * N4];
    wait_cnt(fcc + (l * 12 + jtf) * 16, 24);
    if (tid < 64) xs[tid] = gelu(wfc[e0 + tid]);
    __syncthreads();
    float4 acc = {0.f, 0.f, 0.f, 0.f};
#pragma unroll
    for (int i = 0; i < 16; i++) {
      float x = xs[wid + i * 4];
      acc.x += x * w[i].x; acc.y += x * w[i].y; acc.z += x * w[i].z; acc.w += x * w[i].w;
    }
    red[wid * 64 + lane] = acc;
    __syncthreads();
    if (wid == 0) {
      float4 a0 = red[lane], a1 = red[64 + lane], a2 = red[128 + lane], a3 = red[192 + lane];
      float rx = a0.x + a1.x + a2.x + a3.x;
      float ry = a0.y + a1.y + a2.y + a3.y;
      float rz = a0.z + a1.z + a2.z + a3.z;
      float rw = a0.w + a1.w + a2.w + a3.w;
      if (et2 == 0) {
        const float* bp = mlp_b + l * EMB + j4 * 4;
        rx += bp[0]; ry += bp[1]; rz += bp[2]; rw += bp[3];
      }
      float* op = wsf + WS_H + (size_t)j4 * 4;
      atomicAdd(op + 0, rx); atomicAdd(op + 1, ry);
      atomicAdd(op + 2, rz); atomicAdd(op + 3, rw);
    }
  }
}

// final LN fused into logits
__global__ void logits_lnf(const float* __restrict__ hvec, const float* __restrict__ g,
                           const float* __restrict__ b, const float* __restrict__ wte,
                           float* __restrict__ out) {
  __shared__ __align__(16) float4 xs4[192];
  __shared__ float ra[4], rb[4];
  int tid = threadIdx.x, lane = tid & 63, wid = tid >> 6;
  float hv0 = hvec[tid], hv1 = hvec[tid + 256], hv2 = hvec[tid + 512];
  int v = blockIdx.x * 4 + wid;
  float4 a0 = {0,0,0,0}, a1 = {0,0,0,0}, a2 = {0,0,0,0};
  if (v < NV) {
    const float4* row = (const float4*)(wte + (size_t)v * EMB);
    a0 = row[lane]; a1 = row[lane + 64]; a2 = row[lane + 128];
  }
  float s1 = hv0 + hv1 + hv2;
  float s2 = hv0 * hv0 + hv1 * hv1 + hv2 * hv2;
  blockReduce2(s1, s2, ra, rb);
  float mean = s1 * (1.f / EMB);
  float var = s2 * (1.f / EMB) - mean * mean;
  float rstd = rsqrtf(var + 1e-5f);
  ((float*)xs4)[tid]       = (hv0 - mean) * rstd * g[tid]       + b[tid];
  ((float*)xs4)[tid + 256] = (hv1 - mean) * rstd * g[tid + 256] + b[tid + 256];
  ((float*)xs4)[tid + 512] = (hv2 - mean) * rstd * g[tid + 512] + b[tid + 512];
  __syncthreads();
  if (v >= NV) return;
  float4 x0 = xs4[lane], x1 = xs4[lane + 64], x2 = xs4[lane + 128];
  float acc = a0.x * x0.x + a0.y * x0.y + a0.z * x0.z + a0.w * x0.w
            + a1.x * x1.x + a1.y * x1.y + a1.z * x1.z + a1.w * x1.w
            + a2.x * x2.x + a2.y * x2.y + a2.z * x2.z + a2.w * x2.w;
#pragma unroll
  for (int o = 32; o > 0; o >>= 1) acc += __shfl_down(acc, o);
  if (lane == 0) out[v] = acc;
}

extern "C" void kernel_launch(void* const* d_in, const int* in_sizes, int n_in,
                              void* d_out, int out_size, void* d_ws, size_t ws_size,
                              hipStream_t stream) {
  const int* input_ids = (const int*)d_in[0];
  const float* past_key = (const float*)d_in[1];
  const float* past_value = (const float*)d_in[2];
  const float* mask = (const float*)d_in[4];
  const float* wte = (const float*)d_in[5];
  const float* wpe = (const float*)d_in[6];
  const float* ln1_g = (const float*)d_in[7];
  const float* ln1_b = (const float*)d_in[8];
  const float* attn_w = (const float*)d_in[9];
  const float* attn_b = (const float*)d_in[10];
  const float* proj_w = (const float*)d_in[11];
  const float* proj_b = (const float*)d_in[12];
  const float* ln2_g = (const float*)d_in[13];
  const float* ln2_b = (const float*)d_in[14];
  const float* fc_w = (const float*)d_in[15];
  const float* fc_b = (const float*)d_in[16];
  const float* mlp_w = (const float*)d_in[17];
  const float* mlp_b = (const float*)d_in[18];
  const float* lnf_g = (const float*)d_in[19];
  const float* lnf_b = (const float*)d_in[20];

  float* out = (float*)d_out;
  float* out_logits = out;
  float* out_pk = out + NV;
  float* out_pv = out_pk + (size_t)NL * NH * MAXS * HD;
  float* wsf = (float*)d_ws;

  init_kernel<<<4, 256, 0, stream>>>(input_ids, wte, wpe, wsf);

  for (int l = 0; l < NL; l++) {
    kA<<<408, 256, 0, stream>>>(past_key, past_value, mask, ln1_g, ln1_b, attn_w, attn_b,
                                proj_w, proj_b, fc_b, out_pk, out_pv, wsf, l);
    kB<<<432, 256, 0, stream>>>(ln2_g, ln2_b, fc_w, mlp_w, mlp_b, wsf, l);
  }
  logits_lnf<<<12565, 256, 0, stream>>>(wsf + WS_H, lnf_g, lnf_b, wte, out_logits);
}

// Round 9
// 500.503 us; speedup vs baseline: 3.1932x; 3.1932x over previous
//
#include <hip/hip_runtime.h>
#include <math.h>

#define EMB 768
#define NH 12
#define HD 64
#define NL 12
#define NV 50257
#define MAXS 1024
#define S_PAST 1023
#define E3 2304
#define E4 3072

// workspace float offsets
#define WS_H    0
#define WS_FC   768
#define WS_PART 3840          // 192 * 68
#define WS_VNEW 16896         // 12 heads * 64
#define WS_DOT  17088         // 12 layers * 12 heads

__device__ __forceinline__ void f4add(float4& a, const float4& b) {
  a.x += b.x; a.y += b.y; a.z += b.z; a.w += b.w;
}
__device__ __forceinline__ void f4fma(float4& a, float x, const float4& w) {
  a.x += x * w.x; a.y += x * w.y; a.z += x * w.z; a.w += x * w.w;
}

__device__ __forceinline__ void blockReduce2(float& a, float& b, volatile float* ra, volatile float* rb) {
  int lane = threadIdx.x & 63, wid = threadIdx.x >> 6;
#pragma unroll
  for (int o = 32; o > 0; o >>= 1) { a += __shfl_down(a, o); b += __shfl_down(b, o); }
  if (lane == 0) { ra[wid] = a; rb[wid] = b; }
  __syncthreads();
  if (threadIdx.x == 0) {
    ra[0] = ra[0] + ra[1] + ra[2] + ra[3];
    rb[0] = rb[0] + rb[1] + rb[2] + rb[3];
  }
  __syncthreads();
  a = ra[0]; b = rb[0];
}

__device__ __forceinline__ float gelu(float x) {
  return 0.5f * x * (1.f + tanhf(0.7978845608028654f * (x + 0.044715f * x * x * x)));
}

// h = wte[id]+wpe[S]; zero per-(layer,head) dot accumulators
__global__ void init_kernel(const int* __restrict__ ids, const float* __restrict__ wte,
                            const float* __restrict__ wpe, float* __restrict__ wsf) {
  int tid = threadIdx.x;
  int id = ids[0];
#pragma unroll
  for (int k = 0; k < 3; k++) {
    int e = tid + 256 * k;
    wsf[WS_H + e] = wte[(size_t)id * EMB + e] + wpe[(size_t)S_PAST * EMB + e];
  }
  if (tid < NL * NH) wsf[WS_DOT + tid] = 0.f;
}

// fused qkv+attention: block (chunk c, head h) computes LN1, its own q (full head),
// 4-col slices of k_new/v_new (+dot partial), scores 64 past keys, softmax partial,
// PV partial, and copies its K/V chunk to the output cache.
__global__ void attn_fused(const float* __restrict__ pk, const float* __restrict__ pv,
                           const float* __restrict__ mask,
                           const float* __restrict__ ln1_g, const float* __restrict__ ln1_b,
                           const float* __restrict__ attn_w, const float* __restrict__ attn_b,
                           float* __restrict__ opk, float* __restrict__ opv,
                           float* __restrict__ wsf, int l) {
  __shared__ __align__(16) float smem[1936];
  float* xs = smem;                         // 768 LN1 output
  volatile float* ra = smem + 768;
  volatile float* rb = smem + 772;
  float4* qls = (float4*)(smem + 776);      // [0..15]=q, [16]=k_new, [17]=v_new
  float* sc = smem + 848;                   // 64 scores
  float4* red = (float4*)(smem + 912);      // 256 float4 scratch
  int bi = blockIdx.x;
  int h = bi % NH, c = bi / NH;             // same-head chunks co-locate on ~2 XCDs
  int tid = threadIdx.x, lane = tid & 63, wid = tid >> 6;
  int sub = tid & 15, grp = tid >> 4;
  const float* wh = wsf + WS_H;
  // issue h loads
  float hv0 = wh[tid], hv1 = wh[tid + 256], hv2 = wh[tid + 512];
  // prefetch K chunk (stays in flight through LN)
  size_t base = ((size_t)(l * NH + h) * MAXS) * HD;
  const float4* K4 = (const float4*)(pk + base);
  const float4* V4 = (const float4*)(pv + base);
  int t0 = c * 64;
  float4 kreg[4];
#pragma unroll
  for (int i = 0; i < 4; i++) {
    int t = t0 + grp + i * 16;
    kreg[i] = K4[(size_t)t * 16 + sub];
  }
  float gv0 = ln1_g[l * EMB + tid], gv1 = ln1_g[l * EMB + tid + 256], gv2 = ln1_g[l * EMB + tid + 512];
  float bv0 = ln1_b[l * EMB + tid], bv1 = ln1_b[l * EMB + tid + 256], bv2 = ln1_b[l * EMB + tid + 512];
  float s1 = hv0 + hv1 + hv2, s2 = hv0 * hv0 + hv1 * hv1 + hv2 * hv2;
  blockReduce2(s1, s2, ra, rb);
  float mean = s1 * (1.f / EMB);
  float var = s2 * (1.f / EMB) - mean * mean;
  float rstd = rsqrtf(var + 1e-5f);
  xs[tid]       = (hv0 - mean) * rstd * gv0 + bv0;
  xs[tid + 256] = (hv1 - mean) * rstd * gv1 + bv1;
  xs[tid + 512] = (hv2 - mean) * rstd * gv2 + bv2;
  __syncthreads();
  // q GEMV: full 768 x 64 for this head (L2-shared across the head's 16 blocks)
  const float4* Wb4 = (const float4*)(attn_w + (size_t)l * EMB * E3);
  const int STR = E3 >> 2;
  const float4* Wq4 = Wb4 + h * 16 + sub;
  float4 qacc = {0.f, 0.f, 0.f, 0.f};
#pragma unroll
  for (int b = 0; b < 4; b++) {
    float4 w[12];
#pragma unroll
    for (int j = 0; j < 12; j++) w[j] = Wq4[(size_t)(grp + 16 * (b * 12 + j)) * STR];
#pragma unroll
    for (int j = 0; j < 12; j++) f4fma(qacc, xs[grp + 16 * (b * 12 + j)], w[j]);
  }
  red[tid] = qacc;
  __syncthreads();
#pragma unroll
  for (int s = 8; s >= 1; s >>= 1) {
    if (tid < s * 16) f4add(red[tid], red[tid + s * 16]);
    __syncthreads();
  }
  if (tid < 16) {
    float4 q = red[tid];
    f4add(q, ((const float4*)(attn_b + l * E3 + h * 64))[tid]);
    qls[tid] = q;
  }
  __syncthreads();
  // k_new / v_new 4-col slices (this block owns cols [c*4, c*4+4) of head h)
  const float4* Wk4 = Wb4 + 192 + h * 16 + c;
  const float4* Wv4 = Wb4 + 384 + h * 16 + c;
  float4 ak = {0.f, 0.f, 0.f, 0.f}, av = {0.f, 0.f, 0.f, 0.f};
  {
    float4 wk[3], wv[3];
#pragma unroll
    for (int j = 0; j < 3; j++) {
      int r = tid + 256 * j;
      wk[j] = Wk4[(size_t)r * STR]; wv[j] = Wv4[(size_t)r * STR];
    }
#pragma unroll
    for (int j = 0; j < 3; j++) {
      int r = tid + 256 * j;
      f4fma(ak, xs[r], wk[j]); f4fma(av, xs[r], wv[j]);
    }
  }
  red[tid] = ak;
  __syncthreads();
#pragma unroll
  for (int s = 128; s >= 1; s >>= 1) {
    if (tid < s) f4add(red[tid], red[tid + s]);
    __syncthreads();
  }
  if (tid == 0) {
    float4 kn = red[0];
    f4add(kn, ((const float4*)(attn_b + l * E3))[192 + h * 16 + c]);
    qls[16] = kn;
  }
  __syncthreads();
  red[tid] = av;
  __syncthreads();
#pragma unroll
  for (int s = 128; s >= 1; s >>= 1) {
    if (tid < s) f4add(red[tid], red[tid + s]);
    __syncthreads();
  }
  if (tid == 0) {
    float4 vn = red[0];
    f4add(vn, ((const float4*)(attn_b + l * E3))[384 + h * 16 + c]);
    float4 kn = qls[16];
    const float* qf = (const float*)qls;
    float d4 = qf[c * 4] * kn.x + qf[c * 4 + 1] * kn.y + qf[c * 4 + 2] * kn.z + qf[c * 4 + 3] * kn.w;
    atomicAdd(wsf + WS_DOT + l * NH + h, d4);
    ((float4*)(opk + base))[(size_t)S_PAST * 16 + c] = kn;
    ((float4*)(opv + base))[(size_t)S_PAST * 16 + c] = vn;
    ((float4*)(wsf + WS_VNEW))[h * 16 + c] = vn;
  }
  // scores over this chunk's 64 keys (slot S_PAST masked out; handled in proj)
  float4 q4 = qls[sub];
#pragma unroll
  for (int i = 0; i < 4; i++) {
    int key = grp + i * 16;
    int t = t0 + key;
    float p = q4.x * kreg[i].x + q4.y * kreg[i].y + q4.z * kreg[i].z + q4.w * kreg[i].w;
    p += __shfl_xor(p, 1); p += __shfl_xor(p, 2);
    p += __shfl_xor(p, 4); p += __shfl_xor(p, 8);
    if (sub == 0) sc[key] = (t == S_PAST) ? -1e9f : p * 0.125f + (1.f - mask[t]) * (-1e9f);
  }
  // V prefetch (needed from PV onward)
  float4 vreg[4];
#pragma unroll
  for (int i = 0; i < 4; i++) {
    int t = t0 + grp + i * 16;
    vreg[i] = V4[(size_t)t * 16 + sub];
  }
  __syncthreads();
  float* part = wsf + WS_PART;
  if (wid == 0) {
    float a = sc[lane];
    float m = a;
#pragma unroll
    for (int o = 32; o > 0; o >>= 1) m = fmaxf(m, __shfl_down(m, o));
    m = __shfl(m, 0);
    float ea = expf(a - m);
    sc[lane] = ea;
    float s = ea;
#pragma unroll
    for (int o = 32; o > 0; o >>= 1) s += __shfl_down(s, o);
    if (lane == 0) { part[(h * 16 + c) * 68 + 0] = m; part[(h * 16 + c) * 68 + 1] = s; }
  }
  __syncthreads();
  float4 acc = {0.f, 0.f, 0.f, 0.f};
#pragma unroll
  for (int i = 0; i < 4; i++) {
    float w = sc[grp + i * 16];
    f4fma(acc, w, vreg[i]);
  }
  acc.x += __shfl_xor(acc.x, 16); acc.y += __shfl_xor(acc.y, 16);
  acc.z += __shfl_xor(acc.z, 16); acc.w += __shfl_xor(acc.w, 16);
  acc.x += __shfl_xor(acc.x, 32); acc.y += __shfl_xor(acc.y, 32);
  acc.z += __shfl_xor(acc.z, 32); acc.w += __shfl_xor(acc.w, 32);
  if (lane < 16) red[wid * 16 + lane] = acc;
  __syncthreads();
  if (tid < 16) {
    float4 a0 = red[tid], a1 = red[16 + tid], a2 = red[32 + tid], a3 = red[48 + tid];
    float4 r;
    r.x = a0.x + a1.x + a2.x + a3.x;
    r.y = a0.y + a1.y + a2.y + a3.y;
    r.z = a0.z + a1.z + a2.z + a3.z;
    r.w = a0.w + a1.w + a2.w + a3.w;
    ((float4*)(part + (h * 16 + c) * 68 + 4))[tid] = r;
  }
  // copy this K/V chunk to the output cache (skip slot S_PAST: written above)
#pragma unroll
  for (int i = 0; i < 4; i++) {
    int t = t0 + grp + i * 16;
    if (t != S_PAST) {
      ((float4*)(opk + base))[(size_t)t * 16 + sub] = kreg[i];
      ((float4*)(opv + base))[(size_t)t * 16 + sub] = vreg[i];
    }
  }
}

// combine 16 chunk-partials + new-token term (16-dim slice of head), 16-row GEMV into h
__global__ void proj_attn(const float* __restrict__ W, const float* __restrict__ bias,
                          const float* __restrict__ fc_b, const float* __restrict__ mask,
                          float* __restrict__ hout, float* __restrict__ wsf, int l) {
  int jb = blockIdx.x;           // 0..2 col tile
  int rt = blockIdx.y;           // 0..47 row tile (16 rows)
  int h = rt >> 2, esub = rt & 3;
  int tid = threadIdx.x, lane = tid & 63, wid = tid >> 6;
  __shared__ float xs[16];
  __shared__ float4 red[4][64];
  const float* part = wsf + WS_PART;
  float* wfc = wsf + WS_FC;
  // issue weight loads first
  int j4 = jb * 64 + lane;
  const int N4 = EMB >> 2;
  int r0 = h * 64 + esub * 16;
  const float4* p = (const float4*)(W + (size_t)l * EMB * EMB) + (size_t)(r0 + wid) * N4 + j4;
  float4 w[4];
#pragma unroll
  for (int i = 0; i < 4; i++) w[i] = p[(size_t)(i * 4) * N4];
  if (tid < 16) {
    float dot8 = wsf[WS_DOT + l * NH + h] * 0.125f + (1.f - mask[S_PAST]) * (-1e9f);
    float M = dot8;
#pragma unroll
    for (int q = 0; q < 16; q++) M = fmaxf(M, part[(h * 16 + q) * 68]);
    float en = expf(dot8 - M);
    int d = esub * 16 + tid;
    float T = en, o = en * wsf[WS_VNEW + h * 64 + d];
#pragma unroll
    for (int q = 0; q < 16; q++) {
      float wq = expf(part[(h * 16 + q) * 68] - M);
      T += part[(h * 16 + q) * 68 + 1] * wq;
      o += part[(h * 16 + q) * 68 + 4 + d] * wq;
    }
    xs[tid] = o / T;
  }
  int bid = rt * 3 + jb;
  if (bid < 12) wfc[bid * 256 + tid] = fc_b[l * E4 + bid * 256 + tid];
  __syncthreads();
  float4 acc = {0.f, 0.f, 0.f, 0.f};
#pragma unroll
  for (int i = 0; i < 4; i++) f4fma(acc, xs[wid + i * 4], w[i]);
  red[wid][lane] = acc;
  __syncthreads();
  if (wid == 0) {
    float4 a0 = red[0][lane], a1 = red[1][lane], a2 = red[2][lane], a3 = red[3][lane];
    float rx = a0.x + a1.x + a2.x + a3.x;
    float ry = a0.y + a1.y + a2.y + a3.y;
    float rz = a0.z + a1.z + a2.z + a3.z;
    float rw = a0.w + a1.w + a2.w + a3.w;
    if (rt == 0) {
      const float* bp = bias + l * EMB + jb * 256 + lane * 4;
      rx += bp[0]; ry += bp[1]; rz += bp[2]; rw += bp[3];
    }
    float* op = hout + (size_t)jb * 256 + (size_t)lane * 4;
    atomicAdd(op + 0, rx); atomicAdd(op + 1, ry);
    atomicAdd(op + 2, rz); atomicAdd(op + 3, rw);
  }
}

// fc: wfc[j] += sum_e LN2(h)[e] * fc_w[l][e][j]; 48 rows x 256 cols; 192 blocks
__global__ void fc_gemv(const float* __restrict__ hvec, const float* __restrict__ g,
                        const float* __restrict__ bb, const float* __restrict__ W,
                        float* __restrict__ wfc, int l) {
  __shared__ float lh[EMB];
  __shared__ float xs[48];
  __shared__ float ra[4], rb[4];
  __shared__ float4 red[4][64];
  int tid = threadIdx.x, lane = tid & 63, wid = tid >> 6;
  int jt = blockIdx.x, et = blockIdx.y;
  int e0 = et * 48;
  float hv0 = hvec[tid], hv1 = hvec[tid + 256], hv2 = hvec[tid + 512];
  int j4 = jt * 64 + lane;
  const int N4 = E4 >> 2;
  const float4* p = (const float4*)(W + (size_t)l * EMB * E4) + (size_t)(e0 + wid) * N4 + j4;
  float4 w[12];
#pragma unroll
  for (int i = 0; i < 12; i++) w[i] = p[(size_t)(i * 4) * N4];
  float gv = 0.f, bv = 0.f;
  if (tid < 48) { gv = g[l * EMB + e0 + tid]; bv = bb[l * EMB + e0 + tid]; }
  lh[tid] = hv0; lh[tid + 256] = hv1; lh[tid + 512] = hv2;
  float s1 = hv0 + hv1 + hv2, s2 = hv0 * hv0 + hv1 * hv1 + hv2 * hv2;
  blockReduce2(s1, s2, ra, rb);
  float mean = s1 * (1.f / EMB);
  float var = s2 * (1.f / EMB) - mean * mean;
  float rstd = rsqrtf(var + 1e-5f);
  if (tid < 48) xs[tid] = (lh[e0 + tid] - mean) * rstd * gv + bv;
  __syncthreads();
  float4 acc = {0.f, 0.f, 0.f, 0.f};
#pragma unroll
  for (int i = 0; i < 12; i++) f4fma(acc, xs[wid + i * 4], w[i]);
  red[wid][lane] = acc;
  __syncthreads();
  if (wid == 0) {
    float4 a0 = red[0][lane], a1 = red[1][lane], a2 = red[2][lane], a3 = red[3][lane];
    float rx = a0.x + a1.x + a2.x + a3.x;
    float ry = a0.y + a1.y + a2.y + a3.y;
    float rz = a0.z + a1.z + a2.z + a3.z;
    float rw = a0.w + a1.w + a2.w + a3.w;
    float* op = wfc + (size_t)j4 * 4;
    atomicAdd(op + 0, rx); atomicAdd(op + 1, ry);
    atomicAdd(op + 2, rz); atomicAdd(op + 3, rw);
  }
}

// mlp: h[j] += sum_e gelu(fc[e]) * mlp_w[l][e][j]; 64 rows x 256 cols; 144 blocks
__global__ void mlp_gemv4(const float* __restrict__ fcv, const float* __restrict__ W,
                          const float* __restrict__ bias, float* __restrict__ hout, int l) {
  __shared__ float xs[64];
  __shared__ float4 red[4][64];
  int tid = threadIdx.x, lane = tid & 63, wid = tid >> 6;
  int e0 = blockIdx.y * 64;
  int j4 = blockIdx.x * 64 + lane;
  const int N4 = EMB >> 2;
  const float4* p = (const float4*)(W + (size_t)l * E4 * EMB) + (size_t)(e0 + wid) * N4 + j4;
  float4 w[16];
#pragma unroll
  for (int i = 0; i < 16; i++) w[i] = p[(size_t)(i * 4) * N4];
  if (tid < 64) xs[tid] = gelu(fcv[e0 + tid]);
  __syncthreads();
  float4 acc = {0.f, 0.f, 0.f, 0.f};
#pragma unroll
  for (int i = 0; i < 16; i++) f4fma(acc, xs[wid + i * 4], w[i]);
  red[wid][lane] = acc;
  __syncthreads();
  if (wid == 0) {
    float4 a0 = red[0][lane], a1 = red[1][lane], a2 = red[2][lane], a3 = red[3][lane];
    float rx = a0.x + a1.x + a2.x + a3.x;
    float ry = a0.y + a1.y + a2.y + a3.y;
    float rz = a0.z + a1.z + a2.z + a3.z;
    float rw = a0.w + a1.w + a2.w + a3.w;
    if (blockIdx.y == 0) {
      const float* bp = bias + l * EMB + j4 * 4;
      rx += bp[0]; ry += bp[1]; rz += bp[2]; rw += bp[3];
    }
    float* op = hout + (size_t)j4 * 4;
    atomicAdd(op + 0, rx); atomicAdd(op + 1, ry);
    atomicAdd(op + 2, rz); atomicAdd(op + 3, rw);
  }
}

// final LN fused into logits
__global__ void logits_lnf(const float* __restrict__ hvec, const float* __restrict__ g,
                           const float* __restrict__ b, const float* __restrict__ wte,
                           float* __restrict__ out) {
  __shared__ __align__(16) float4 xs4[192];
  __shared__ float ra[4], rb[4];
  int tid = threadIdx.x, lane = tid & 63, wid = tid >> 6;
  float hv0 = hvec[tid], hv1 = hvec[tid + 256], hv2 = hvec[tid + 512];
  int v = blockIdx.x * 4 + wid;
  float4 a0 = {0,0,0,0}, a1 = {0,0,0,0}, a2 = {0,0,0,0};
  if (v < NV) {
    const float4* row = (const float4*)(wte + (size_t)v * EMB);
    a0 = row[lane]; a1 = row[lane + 64]; a2 = row[lane + 128];
  }
  float s1 = hv0 + hv1 + hv2;
  float s2 = hv0 * hv0 + hv1 * hv1 + hv2 * hv2;
  blockReduce2(s1, s2, ra, rb);
  float mean = s1 * (1.f / EMB);
  float var = s2 * (1.f / EMB) - mean * mean;
  float rstd = rsqrtf(var + 1e-5f);
  ((float*)xs4)[tid]       = (hv0 - mean) * rstd * g[tid]       + b[tid];
  ((float*)xs4)[tid + 256] = (hv1 - mean) * rstd * g[tid + 256] + b[tid + 256];
  ((float*)xs4)[tid + 512] = (hv2 - mean) * rstd * g[tid + 512] + b[tid + 512];
  __syncthreads();
  if (v >= NV) return;
  float4 x0 = xs4[lane], x1 = xs4[lane + 64], x2 = xs4[lane + 128];
  float acc = a0.x * x0.x + a0.y * x0.y + a0.z * x0.z + a0.w * x0.w
            + a1.x * x1.x + a1.y * x1.y + a1.z * x1.z + a1.w * x1.w
            + a2.x * x2.x + a2.y * x2.y + a2.z * x2.z + a2.w * x2.w;
#pragma unroll
  for (int o = 32; o > 0; o >>= 1) acc += __shfl_down(acc, o);
  if (lane == 0) out[v] = acc;
}

extern "C" void kernel_launch(void* const* d_in, const int* in_sizes, int n_in,
                              void* d_out, int out_size, void* d_ws, size_t ws_size,
                              hipStream_t stream) {
  const int* input_ids = (const int*)d_in[0];
  const float* past_key = (const float*)d_in[1];
  const float* past_value = (const float*)d_in[2];
  const float* mask = (const float*)d_in[4];
  const float* wte = (const float*)d_in[5];
  const float* wpe = (const float*)d_in[6];
  const float* ln1_g = (const float*)d_in[7];
  const float* ln1_b = (const float*)d_in[8];
  const float* attn_w = (const float*)d_in[9];
  const float* attn_b = (const float*)d_in[10];
  const float* proj_w = (const float*)d_in[11];
  const float* proj_b = (const float*)d_in[12];
  const float* ln2_g = (const float*)d_in[13];
  const float* ln2_b = (const float*)d_in[14];
  const float* fc_w = (const float*)d_in[15];
  const float* fc_b = (const float*)d_in[16];
  const float* mlp_w = (const float*)d_in[17];
  const float* mlp_b = (const float*)d_in[18];
  const float* lnf_g = (const float*)d_in[19];
  const float* lnf_b = (const float*)d_in[20];

  float* out = (float*)d_out;
  float* out_logits = out;
  float* out_pk = out + NV;
  float* out_pv = out_pk + (size_t)NL * NH * MAXS * HD;
  float* wsf = (float*)d_ws;
  float* wh = wsf + WS_H;
  float* wfc = wsf + WS_FC;

  init_kernel<<<1, 256, 0, stream>>>(input_ids, wte, wpe, wsf);

  for (int l = 0; l < NL; l++) {
    attn_fused<<<192, 256, 0, stream>>>(past_key, past_value, mask, ln1_g, ln1_b,
                                        attn_w, attn_b, out_pk, out_pv, wsf, l);
    proj_attn<<<dim3(3, 48), 256, 0, stream>>>(proj_w, proj_b, fc_b, mask, wh, wsf, l);
    fc_gemv<<<dim3(12, 16), 256, 0, stream>>>(wh, ln2_g, ln2_b, fc_w, wfc, l);
    mlp_gemv4<<<dim3(3, 48), 256, 0, stream>>>(wfc, mlp_w, mlp_b, wh, l);
  }
  logits_lnf<<<12565, 256, 0, stream>>>(wh, lnf_g, lnf_b, wte, out_logits);
}